// Round 5
// baseline (185.024 us; speedup 1.0000x reference)
//
#include <hip/hip_runtime.h>
#include <stdint.h>

typedef __attribute__((ext_vector_type(8))) __bf16 bf16x8;
typedef __attribute__((ext_vector_type(8))) unsigned short ushort8;
typedef __attribute__((ext_vector_type(4))) float f32x4;

static __device__ __forceinline__ unsigned short f2bf(float f) {
  unsigned u = __float_as_uint(f);
  u += 0x7fffu + ((u >> 16) & 1u);
  return (unsigned short)(u >> 16);
}

union U16cast { ushort8 u; bf16x8 b; };
static __device__ __forceinline__ bf16x8 as_bf16x8(ushort8 x) { U16cast t; t.u = x; return t.b; }
static __device__ __forceinline__ bf16x8 ldfrag(const unsigned short* p) {
  return as_bf16x8(*(const ushort8*)p);
}

#define MFMA16(a, b, c) __builtin_amdgcn_mfma_f32_16x16x32_bf16((a), (b), (c), 0, 0, 0)

#define GLD_LDS16(g, l)                                                        \
  __builtin_amdgcn_global_load_lds(                                            \
      (const __attribute__((address_space(1))) void*)(g),                      \
      (__attribute__((address_space(3))) void*)(l), 16, 0, 0)

// ---------------- merged cast f32 -> bf16 + zero l ---------------------------
__global__ __launch_bounds__(256) void cast_all(
    const float* __restrict__ x, const float* __restrict__ Wq,
    const float* __restrict__ Wk, const float* __restrict__ Wv,
    unsigned short* __restrict__ out, float* __restrict__ lzero,
    long nx4, long nw4, long n4) {
  long g = (long)blockIdx.x * blockDim.x + threadIdx.x;
  if (g < 2048) ((float4*)lzero)[g] = (float4){0.f, 0.f, 0.f, 0.f};  // l[8192]=0
  long i = g;
  long stride = (long)gridDim.x * blockDim.x;
  for (; i < n4; i += stride) {
    const float4* src;
    long j = i;
    if (j < nx4) {
      src = (const float4*)x;
    } else {
      j -= nx4;
      if (j < nw4) src = (const float4*)Wq;
      else if (j < 2 * nw4) { src = (const float4*)Wk; j -= nw4; }
      else { src = (const float4*)Wv; j -= 2 * nw4; }
    }
    float4 v = src[j];
    ushort4 o;
    o.x = f2bf(v.x); o.y = f2bf(v.y); o.z = f2bf(v.z); o.w = f2bf(v.w);
    *(ushort4*)(out + i * 4) = o;
  }
}

// ============== QKV GEMM v5: 256x256, BK=64, ledger-derived 8-phase =========
// 512 thr (8 waves 2Mx4N), per-wave 128x64, acc[8][4]. LDS 128 KB dbuf.
// Stage unit = 64-row quarter (1 gload x 512thr x 16B). Per tile t issue
// order B01|B23|A02|A13 at t-1 phases 0..3 (matches consume order: ph0 needs
// all B + A{q0,q2}, ph2 needs A{q1,q3}).
// Ledger (steady): t.ph0: +B01(t+1)=10 outstanding, retire thru A2(t) ->
// vmcnt(4); t.ph2: +A02(t+1)=8, retire A13(t) -> vmcnt(6); ph1/ph3 no wait.
// Issue->need distance 2-4 phases; L2-warm loads covered. Tail: vmcnt(2)/0.
// Phase: {gloads, [vmcnt], barrier, ds_reads(12/4/8/0), lgkmcnt(0),
//         sched_barrier, setprio(1), 16 MFMA, setprio(0), barrier}.
// Swizzle: seg' = seg ^ (row&7), 8 segs of 16B per 128B row; read seg =
// ((ksub*4+kb) ^ (fr&7)) -> 2 lanes/bank (free). Pre-swizzled global source.
__global__ __launch_bounds__(512, 2) void gemm_qkv(
    const unsigned short* __restrict__ A, const unsigned short* __restrict__ B,
    unsigned short* __restrict__ qkv, unsigned short* __restrict__ vT) {
  __shared__ __align__(16) unsigned short As[2][16384];  // 64 KB
  __shared__ __align__(16) unsigned short Bs[2][16384];  // 64 KB

  int wg = blockIdx.x;
  wg = (wg & 7) * 48 + (wg >> 3);            // XCD swizzle, 384 = 8*48
  const int bm = wg / 12, bn = wg % 12;
  const int m0 = bm << 8, n0 = bn << 8;

  const int tid = threadIdx.x;
  const int sq = tid >> 3;                   // 0..63 row within quarter
  const int gseg = (tid & 7) ^ (sq & 7);     // pre-swizzled global seg
  const unsigned short* pAg = A + (long)(m0 + sq) * 1024 + gseg * 8;
  const unsigned short* pBg = B + (long)(n0 + sq) * 1024 + gseg * 8;
  unsigned short* dAl = &As[0][0] + tid * 8;
  unsigned short* dBl = &Bs[0][0] + tid * 8;

  // quarter q: global rows q*64.., dest As[buf] + q*4096 shorts
#define SA(q, kt, bo) GLD_LDS16(pAg + (q) * 65536 + (kt) * 64, dAl + (bo) + (q) * 4096)
#define SB(q, kt, bo) GLD_LDS16(pBg + (q) * 65536 + (kt) * 64, dBl + (bo) + (q) * 4096)

  const int lane = tid & 63;
  const int w = tid >> 6;
  const int wr = w >> 2;                     // 0..1 (128 M-rows)
  const int wc = w & 3;                      // 0..3 (64 N-cols)
  const int fr = lane & 15;
  const int kb = lane >> 4;
  const int f7 = fr & 7;
  const int s0 = (kb ^ f7) << 3;             // shorts offset of k-seg 0
  const int s1 = s0 ^ 32;                    // k-seg 1 (ksub=1): g=4+kb
  const unsigned short* rA = &As[0][0] + (wr * 128 + fr) * 64;
  const unsigned short* rB = &Bs[0][0] + (wc * 64 + fr) * 64;

  f32x4 acc[8][4];
#pragma unroll
  for (int mf = 0; mf < 8; ++mf)
#pragma unroll
    for (int nf = 0; nf < 4; ++nf)
      acc[mf][nf] = (f32x4){0.f, 0.f, 0.f, 0.f};

  bf16x8 av[4][2], b0[2][2], b1[2][2];

  // prologue: tile 0, queue order B0,B1,B2,B3,A0,A2,A1,A3
  SB(0, 0, 0); SB(1, 0, 0); SB(2, 0, 0); SB(3, 0, 0);
  SA(0, 0, 0); SA(2, 0, 0); SA(1, 0, 0); SA(3, 0, 0);

#pragma unroll 1
  for (int t = 0; t < 16; ++t) {
    const int bo = (t & 1) << 14;
    const int bo1 = bo ^ 16384;
    const int k1 = t + 1;
    const bool nl = (t < 15);
    const unsigned short* pa = rA + bo;
    const unsigned short* pb = rB + bo;

    // ---- ph0: quad(mh0,nh0); stage B01(t+1); vmcnt(4|2) -------------------
    if (nl) { SB(0, k1, bo1); SB(1, k1, bo1); }
    if (nl) asm volatile("s_waitcnt vmcnt(4)" ::: "memory");
    else    asm volatile("s_waitcnt vmcnt(2)" ::: "memory");
    __builtin_amdgcn_s_barrier();
    __builtin_amdgcn_sched_barrier(0);
#pragma unroll
    for (int mf = 0; mf < 4; ++mf) {
      av[mf][0] = ldfrag(pa + mf * 1024 + s0);
      av[mf][1] = ldfrag(pa + mf * 1024 + s1);
    }
#pragma unroll
    for (int nf = 0; nf < 2; ++nf) {
      b0[nf][0] = ldfrag(pb + nf * 1024 + s0);
      b0[nf][1] = ldfrag(pb + nf * 1024 + s1);
    }
    asm volatile("s_waitcnt lgkmcnt(0)" ::: "memory");
    __builtin_amdgcn_sched_barrier(0);
    __builtin_amdgcn_s_setprio(1);
#pragma unroll
    for (int mf = 0; mf < 4; ++mf)
#pragma unroll
      for (int nf = 0; nf < 2; ++nf) {
        acc[mf][nf] = MFMA16(av[mf][0], b0[nf][0], acc[mf][nf]);
        acc[mf][nf] = MFMA16(av[mf][1], b0[nf][1], acc[mf][nf]);
      }
    __builtin_amdgcn_s_setprio(0);
    __builtin_amdgcn_s_barrier();

    // ---- ph1: quad(mh0,nh1); stage B23(t+1) -------------------------------
    if (nl) { SB(2, k1, bo1); SB(3, k1, bo1); }
    __builtin_amdgcn_s_barrier();
    __builtin_amdgcn_sched_barrier(0);
#pragma unroll
    for (int nf = 0; nf < 2; ++nf) {
      b1[nf][0] = ldfrag(pb + 2048 + nf * 1024 + s0);
      b1[nf][1] = ldfrag(pb + 2048 + nf * 1024 + s1);
    }
    asm volatile("s_waitcnt lgkmcnt(0)" ::: "memory");
    __builtin_amdgcn_sched_barrier(0);
    __builtin_amdgcn_s_setprio(1);
#pragma unroll
    for (int mf = 0; mf < 4; ++mf)
#pragma unroll
      for (int nf = 0; nf < 2; ++nf) {
        acc[mf][2 + nf] = MFMA16(av[mf][0], b1[nf][0], acc[mf][2 + nf]);
        acc[mf][2 + nf] = MFMA16(av[mf][1], b1[nf][1], acc[mf][2 + nf]);
      }
    __builtin_amdgcn_s_setprio(0);
    __builtin_amdgcn_s_barrier();

    // ---- ph2: quad(mh1,nh0); stage A02(t+1); vmcnt(6|0) -------------------
    if (nl) { SA(0, k1, bo1); SA(2, k1, bo1); }
    if (nl) asm volatile("s_waitcnt vmcnt(6)" ::: "memory");
    else    asm volatile("s_waitcnt vmcnt(0)" ::: "memory");
    __builtin_amdgcn_s_barrier();
    __builtin_amdgcn_sched_barrier(0);
#pragma unroll
    for (int mf = 0; mf < 4; ++mf) {
      av[mf][0] = ldfrag(pa + 4096 + mf * 1024 + s0);
      av[mf][1] = ldfrag(pa + 4096 + mf * 1024 + s1);
    }
    asm volatile("s_waitcnt lgkmcnt(0)" ::: "memory");
    __builtin_amdgcn_sched_barrier(0);
    __builtin_amdgcn_s_setprio(1);
#pragma unroll
    for (int mf = 0; mf < 4; ++mf)
#pragma unroll
      for (int nf = 0; nf < 2; ++nf) {
        acc[4 + mf][nf] = MFMA16(av[mf][0], b0[nf][0], acc[4 + mf][nf]);
        acc[4 + mf][nf] = MFMA16(av[mf][1], b0[nf][1], acc[4 + mf][nf]);
      }
    __builtin_amdgcn_s_setprio(0);
    __builtin_amdgcn_s_barrier();

    // ---- ph3: quad(mh1,nh1); stage A13(t+1); no reads ---------------------
    if (nl) { SA(1, k1, bo1); SA(3, k1, bo1); }
    __builtin_amdgcn_s_barrier();
    __builtin_amdgcn_sched_barrier(0);
    __builtin_amdgcn_s_setprio(1);
#pragma unroll
    for (int mf = 0; mf < 4; ++mf)
#pragma unroll
      for (int nf = 0; nf < 2; ++nf) {
        acc[4 + mf][2 + nf] = MFMA16(av[mf][0], b1[nf][0], acc[4 + mf][2 + nf]);
        acc[4 + mf][2 + nf] = MFMA16(av[mf][1], b1[nf][1], acc[4 + mf][2 + nf]);
      }
    __builtin_amdgcn_s_setprio(0);
    __builtin_amdgcn_s_barrier();
  }
#undef SA
#undef SB

  // ---- epilogue ------------------------------------------------------------
  const int rq = kb << 2;
  if (n0 < 2048) {  // q,k tiles
#pragma unroll
    for (int mfg = 0; mfg < 8; ++mfg) {
      const int row = m0 + wr * 128 + mfg * 16 + rq;
#pragma unroll
      for (int nfg = 0; nfg < 4; ++nfg) {
        const int col = n0 + wc * 64 + nfg * 16 + fr;
#pragma unroll
        for (int r = 0; r < 4; ++r)
          qkv[(long)(row + r) * 3072 + col] = f2bf(acc[mfg][nfg][r]);
      }
    }
  } else {  // v tiles: transposed scatter into vT[b][1024][2048]
    const int b2 = m0 >> 11;
    const int t0v = (m0 & 2047) + wr * 128;
#pragma unroll
    for (int mfg = 0; mfg < 8; ++mfg) {
      const int trow = t0v + mfg * 16 + rq;
#pragma unroll
      for (int nfg = 0; nfg < 4; ++nfg) {
        const int colv = (n0 - 2048) + wc * 64 + nfg * 16 + fr;
        ushort4 o;
        o.x = f2bf(acc[mfg][nfg][0]); o.y = f2bf(acc[mfg][nfg][1]);
        o.z = f2bf(acc[mfg][nfg][2]); o.w = f2bf(acc[mfg][nfg][3]);
        *(ushort4*)(vT + ((long)b2 * 1024 + colv) * 2048 + trow) = o;
      }
    }
  }
}

// ---------------- 128x128 GEMM engine for S and PV (r0-proven) --------------
template <int MODE>
__global__ __launch_bounds__(256, 4) void gemm128(
    const unsigned short* __restrict__ A, const unsigned short* __restrict__ Bp,
    void* __restrict__ Cout, float* __restrict__ lbuf) {
  __shared__ __align__(16) unsigned short As[2][4096];
  __shared__ __align__(16) unsigned short Bs[2][4096];

  constexpr int LDA = (MODE == 1) ? 3072 : 2048;

  const int wgid = blockIdx.x;
  int m0, n0, b;
  if constexpr (MODE == 1) {
    b = wgid & 3;
    const int t = wgid >> 2;                    // 0..135
    int bm = 0;
    while ((bm + 2) * (bm + 1) / 2 <= t) ++bm;
    const int bn = t - bm * (bm + 1) / 2;
    m0 = bm << 7; n0 = bn << 7;
  } else {
    const int xcd = wgid & 7;
    const int inner = wgid >> 3;                // 0..63
    const int s = inner >> 5;
    const int rem = inner & 31;
    b = rem >> 3;
    const int bn = rem & 7;
    const int bm = s ? (15 - xcd) : xcd;
    m0 = bm << 7; n0 = bn << 7;
  }

  const unsigned short* Ab = A;
  const unsigned short* Bb = Bp;
  if constexpr (MODE == 1) {
    Ab += (long)b * 2048 * 3072;
    Bb += (long)b * 2048 * 3072;
  } else {
    Ab += (long)b * 2048 * 2048;
    Bb += (long)b * 1024 * 2048;
  }

  const int tid = threadIdx.x;

  const int srow = tid >> 2;                       // 0..63
  const int sseg = (tid & 3) ^ ((srow >> 1) & 3);
  const unsigned short* sa = Ab + (long)(m0 + srow) * LDA + sseg * 8;
  const unsigned short* sb = Bb + (long)(n0 + srow) * LDA + sseg * 8;
  const long sRj = (long)64 * LDA;
  unsigned short* dA = &As[0][0] + tid * 8;
  unsigned short* dB = &Bs[0][0] + tid * 8;

#define STG(kt, s)                                                             \
  do {                                                                         \
    GLD_LDS16(sa + (kt) * 32, dA + (s) * 4096);                                \
    GLD_LDS16(sa + sRj + (kt) * 32, dA + (s) * 4096 + 2048);                   \
    GLD_LDS16(sb + (kt) * 32, dB + (s) * 4096);                                \
    GLD_LDS16(sb + sRj + (kt) * 32, dB + (s) * 4096 + 2048);                   \
  } while (0)

  const int lane = tid & 63;
  const int w = tid >> 6;
  const int wr = w >> 1;
  const int wc = w & 1;
  const int fr = lane & 15;
  const int kb = lane >> 4;
  const unsigned short* rA0 = &As[0][0] + wr * 64 * 32;
  const unsigned short* rB0 = &Bs[0][0] + wc * 64 * 32;

  f32x4 acc[4][4];
#pragma unroll
  for (int mf = 0; mf < 4; ++mf)
#pragma unroll
    for (int nf = 0; nf < 4; ++nf)
      acc[mf][nf] = (f32x4){0.f, 0.f, 0.f, 0.f};

  const int kend = (MODE == 2) ? (m0 + 128) : 1024;
  const int NT = kend >> 5;

  STG(0, 0);
  __syncthreads();

  for (int kt = 0; kt < NT; ++kt) {
    const int s = kt & 1;
    if (kt + 1 < NT) STG(kt + 1, s ^ 1);

    bf16x8 av[4], bvv[4];
#pragma unroll
    for (int mf = 0; mf < 4; ++mf) {
      const int row = mf * 16 + fr;
      const int segr = (kb ^ ((row >> 1) & 3)) << 3;
      av[mf] = ldfrag(rA0 + s * 4096 + row * 32 + segr);
    }
#pragma unroll
    for (int nf = 0; nf < 4; ++nf) {
      const int row = nf * 16 + fr;
      const int segr = (kb ^ ((row >> 1) & 3)) << 3;
      bvv[nf] = ldfrag(rB0 + s * 4096 + row * 32 + segr);
    }

#pragma unroll
    for (int mf = 0; mf < 4; ++mf)
#pragma unroll
      for (int nf = 0; nf < 4; ++nf)
        acc[mf][nf] = MFMA16(av[mf], bvv[nf], acc[mf][nf]);

    __syncthreads();
  }
#undef STG

  const int rq = kb << 2;
  if constexpr (MODE == 1) {
    unsigned short* Pu = (unsigned short*)Cout + (long)b * 2048 * 2048;
    float* lrow = lbuf + b * 2048;
#pragma unroll
    for (int mf = 0; mf < 4; ++mf) {
      const int row = m0 + wr * 64 + mf * 16 + rq;
      float psum0 = 0.f, psum1 = 0.f, psum2 = 0.f, psum3 = 0.f;
#pragma unroll
      for (int nf = 0; nf < 4; ++nf) {
        const int col = n0 + wc * 64 + nf * 16 + fr;
        float e0 = (col > row + 0) ? 0.f : __expf(acc[mf][nf][0] * 0.03125f);
        float e1 = (col > row + 1) ? 0.f : __expf(acc[mf][nf][1] * 0.03125f);
        float e2 = (col > row + 2) ? 0.f : __expf(acc[mf][nf][2] * 0.03125f);
        float e3 = (col > row + 3) ? 0.f : __expf(acc[mf][nf][3] * 0.03125f);
        psum0 += e0; psum1 += e1; psum2 += e2; psum3 += e3;
        Pu[(long)(row + 0) * 2048 + col] = f2bf(e0);
        Pu[(long)(row + 1) * 2048 + col] = f2bf(e1);
        Pu[(long)(row + 2) * 2048 + col] = f2bf(e2);
        Pu[(long)(row + 3) * 2048 + col] = f2bf(e3);
      }
#pragma unroll
      for (int off = 1; off < 16; off <<= 1) {
        psum0 += __shfl_xor(psum0, off);
        psum1 += __shfl_xor(psum1, off);
        psum2 += __shfl_xor(psum2, off);
        psum3 += __shfl_xor(psum3, off);
      }
      if (fr == 0) {
        atomicAdd(&lrow[row + 0], psum0);
        atomicAdd(&lrow[row + 1], psum1);
        atomicAdd(&lrow[row + 2], psum2);
        atomicAdd(&lrow[row + 3], psum3);
      }
    }
  } else {
    float* Cf = (float*)Cout + (long)b * 2048 * 1024;
    const float* lrow = lbuf + b * 2048;
#pragma unroll
    for (int mf = 0; mf < 4; ++mf) {
      const int row = m0 + wr * 64 + mf * 16 + rq;
      float il0 = 1.0f / lrow[row + 0];
      float il1 = 1.0f / lrow[row + 1];
      float il2 = 1.0f / lrow[row + 2];
      float il3 = 1.0f / lrow[row + 3];
#pragma unroll
      for (int nf = 0; nf < 4; ++nf) {
        const int col = n0 + wc * 64 + nf * 16 + fr;
        Cf[(long)(row + 0) * 1024 + col] = acc[mf][nf][0] * il0;
        Cf[(long)(row + 1) * 1024 + col] = acc[mf][nf][1] * il1;
        Cf[(long)(row + 2) * 1024 + col] = acc[mf][nf][2] * il2;
        Cf[(long)(row + 3) * 1024 + col] = acc[mf][nf][3] * il3;
      }
    }
  }
}

// ---------------------------------------------------------------------------
extern "C" void kernel_launch(void* const* d_in, const int* in_sizes, int n_in,
                              void* d_out, int out_size, void* d_ws, size_t ws_size,
                              hipStream_t stream) {
  const float* x  = (const float*)d_in[0];
  const float* Wq = (const float*)d_in[1];
  const float* Wk = (const float*)d_in[2];
  const float* Wv = (const float*)d_in[3];
  float* out = (float*)d_out;

  const int Bb = 4, T = 2048, C = 1024;
  const long BT = (long)Bb * T;  // 8192
  const int N3 = 3 * C;          // 3072

  char* ws = (char*)d_ws;
  unsigned short* xb   = (unsigned short*)ws; ws += BT * C * 2;            // 16 MB
  unsigned short* wbuf = (unsigned short*)ws; ws += (long)N3 * C * 2;      // 6 MB
  unsigned short* qkv  = (unsigned short*)ws; ws += BT * N3 * 2;           // 48 MB (v cols unused)
  unsigned short* vT   = (unsigned short*)ws; ws += BT * C * 2;            // 16 MB
  unsigned short* Pu   = (unsigned short*)ws; ws += (long)Bb * T * T * 2;  // 32 MB
  float* lbuf          = (float*)ws;          ws += BT * 4;                // 32 KB

  // 1. merged casts + zero l
  const long nx4 = BT * C / 4, nw4 = (long)C * C / 4;
  cast_all<<<2048, 256, 0, stream>>>(x, Wq, Wk, Wv, xb, lbuf, nx4, nw4, nx4 + 3 * nw4);

  // 2. fused QKV projection (256x256 ledger 8-phase); v -> vT transposed
  gemm_qkv<<<dim3(384, 1, 1), 512, 0, stream>>>(xb, wbuf, qkv, vT);

  // 3. Pu = exp(q k^T / 32) (causal, no-max softmax) + atomic row sums -> l
  gemm128<1><<<dim3(544, 1, 1), 256, 0, stream>>>(qkv, qkv + C, Pu, lbuf);

  // 4. out = (Pu vT) / l (causal K, XCD-banded bn-sweep + per-XCD LPT)
  gemm128<2><<<dim3(512, 1, 1), 256, 0, stream>>>(Pu, vT, out, lbuf);
}

// Round 6
// 156.006 us; speedup vs baseline: 1.1860x; 1.1860x over previous
//
#include <hip/hip_runtime.h>
#include <stdint.h>

typedef __attribute__((ext_vector_type(8))) __bf16 bf16x8;
typedef __attribute__((ext_vector_type(8))) unsigned short ushort8;
typedef __attribute__((ext_vector_type(4))) float f32x4;

static __device__ __forceinline__ unsigned short f2bf(float f) {
  unsigned u = __float_as_uint(f);
  u += 0x7fffu + ((u >> 16) & 1u);
  return (unsigned short)(u >> 16);
}

union U16cast { ushort8 u; bf16x8 b; };
static __device__ __forceinline__ bf16x8 as_bf16x8(ushort8 x) { U16cast t; t.u = x; return t.b; }
static __device__ __forceinline__ bf16x8 ldfrag(const unsigned short* p) {
  return as_bf16x8(*(const ushort8*)p);
}

#define GLD_LDS16(g, l)                                                        \
  __builtin_amdgcn_global_load_lds(                                            \
      (const __attribute__((address_space(1))) void*)(g),                      \
      (__attribute__((address_space(3))) void*)(l), 16, 0, 0)

// ---------------- merged cast f32 -> bf16 + zero l ---------------------------
__global__ __launch_bounds__(256) void cast_all(
    const float* __restrict__ x, const float* __restrict__ Wq,
    const float* __restrict__ Wk, const float* __restrict__ Wv,
    unsigned short* __restrict__ out, float* __restrict__ lzero,
    long nx4, long nw4, long n4) {
  long g = (long)blockIdx.x * blockDim.x + threadIdx.x;
  if (g < 2048) ((float4*)lzero)[g] = (float4){0.f, 0.f, 0.f, 0.f};  // l[8192]=0
  long i = g;
  long stride = (long)gridDim.x * blockDim.x;
  for (; i < n4; i += stride) {
    const float4* src;
    long j = i;
    if (j < nx4) {
      src = (const float4*)x;
    } else {
      j -= nx4;
      if (j < nw4) src = (const float4*)Wq;
      else if (j < 2 * nw4) { src = (const float4*)Wk; j -= nw4; }
      else { src = (const float4*)Wv; j -= 2 * nw4; }
    }
    float4 v = src[j];
    ushort4 o;
    o.x = f2bf(v.x); o.y = f2bf(v.y); o.z = f2bf(v.z); o.w = f2bf(v.w);
    *(ushort4*)(out + i * 4) = o;
  }
}

// ---------------- QKV GEMM: 128x256 tile, BK=32, 8 waves (r0-proven) --------
__global__ __launch_bounds__(512, 4) void gemm_qkv(
    const unsigned short* __restrict__ A, const unsigned short* __restrict__ B,
    unsigned short* __restrict__ qkv, unsigned short* __restrict__ vT) {
  __shared__ __align__(16) unsigned short As[2][4096];   // [buf][128*32]
  __shared__ __align__(16) unsigned short Bs[2][8192];   // [buf][256*32]

  int wg = blockIdx.x;
  wg = (wg & 7) * 96 + (wg >> 3);
  const int bm = wg / 12, bn = wg % 12;
  const int m0 = bm << 7, n0 = bn << 8;

  const int tid = threadIdx.x;

  const int srow = tid >> 2;                       // 0..127
  const int sseg = (tid & 3) ^ ((srow >> 1) & 3);
  const unsigned short* sa = A + (long)(m0 + srow) * 1024 + sseg * 8;
  const unsigned short* sb0 = B + (long)(n0 + srow) * 1024 + sseg * 8;
  const unsigned short* sb1 = sb0 + (long)128 * 1024;
  unsigned short* dA = &As[0][0] + tid * 8;
  unsigned short* dB = &Bs[0][0] + tid * 8;

#define STG(kt, s)                                                             \
  do {                                                                         \
    GLD_LDS16(sa + (kt) * 32, dA + (s) * 4096);                                \
    GLD_LDS16(sb0 + (kt) * 32, dB + (s) * 8192);                               \
    GLD_LDS16(sb1 + (kt) * 32, dB + (s) * 8192 + 4096);                        \
  } while (0)

  const int lane = tid & 63;
  const int w = tid >> 6;
  const int wr = w >> 2;     // 0..1
  const int wc = w & 3;      // 0..3
  const int fr = lane & 15;
  const int kb = lane >> 4;
  const int segr = (kb ^ ((fr >> 1) & 3)) << 3;
  const unsigned short* rA = &As[0][0] + (wr * 64 + fr) * 32 + segr;
  const unsigned short* rB = &Bs[0][0] + (wc * 64 + fr) * 32 + segr;

  f32x4 acc[4][4];
#pragma unroll
  for (int mf = 0; mf < 4; ++mf)
#pragma unroll
    for (int nf = 0; nf < 4; ++nf)
      acc[mf][nf] = (f32x4){0.f, 0.f, 0.f, 0.f};

  STG(0, 0);
  __syncthreads();

  for (int kt = 0; kt < 32; ++kt) {
    const int s = kt & 1;
    if (kt + 1 < 32) STG(kt + 1, s ^ 1);

    const unsigned short* pA = rA + s * 4096;
    const unsigned short* pB = rB + s * 8192;
    bf16x8 av[4], bv[4];
#pragma unroll
    for (int mf = 0; mf < 4; ++mf) av[mf] = ldfrag(pA + mf * 512);
#pragma unroll
    for (int nf = 0; nf < 4; ++nf) bv[nf] = ldfrag(pB + nf * 512);

#pragma unroll
    for (int mf = 0; mf < 4; ++mf)
#pragma unroll
      for (int nf = 0; nf < 4; ++nf)
        acc[mf][nf] = __builtin_amdgcn_mfma_f32_16x16x32_bf16(av[mf], bv[nf], acc[mf][nf], 0, 0, 0);

    __syncthreads();
  }
#undef STG

  const int rq = kb << 2;
  if (n0 < 2048) {  // q,k tiles
#pragma unroll
    for (int mf = 0; mf < 4; ++mf) {
      const int row = m0 + wr * 64 + mf * 16 + rq;
#pragma unroll
      for (int nf = 0; nf < 4; ++nf) {
        const int col = n0 + wc * 64 + nf * 16 + fr;
#pragma unroll
        for (int r = 0; r < 4; ++r)
          qkv[(long)(row + r) * 3072 + col] = f2bf(acc[mf][nf][r]);
      }
    }
  } else {  // v tiles: transposed scatter into vT[b][1024][2048]
    const int b2 = m0 >> 11;
    const int t0 = (m0 & 2047) + wr * 64;
#pragma unroll
    for (int mf = 0; mf < 4; ++mf) {
      const int trow = t0 + mf * 16 + rq;
#pragma unroll
      for (int nf = 0; nf < 4; ++nf) {
        const int colv = (n0 - 2048) + wc * 64 + nf * 16 + fr;
        ushort4 o;
        o.x = f2bf(acc[mf][nf][0]); o.y = f2bf(acc[mf][nf][1]);
        o.z = f2bf(acc[mf][nf][2]); o.w = f2bf(acc[mf][nf][3]);
        *(ushort4*)(vT + ((long)b2 * 1024 + colv) * 2048 + trow) = o;
      }
    }
  }
}

// ---------------- 128x128 GEMM engine for S and PV (r0-proven) --------------
//  MODE 1 S:   triangular grid (544, z fastest): A=q, B=k (stride 3072).
//              Epilogue: Pu = exp(s/32) (causal-masked -> exact 0) stored bf16,
//              plus per-row partial sums reduced over the 16 fr-lanes and
//              atomicAdd'ed into l[b*2048+row].
//  MODE 2 PV:  512 blocks; XCD-banded bn-sweep + per-XCD LPT; causal
//              kend=m0+128; A=Pu, B=vT. Epilogue: out = acc * (1/l[row]);
//              r6: 1/l loads+rcp hoisted ABOVE the K-loop (loop-invariant,
//              latency hidden under MFMA; +16 VGPR, still 4 blocks/CU).
template <int MODE>
__global__ __launch_bounds__(256, 4) void gemm128(
    const unsigned short* __restrict__ A, const unsigned short* __restrict__ Bp,
    void* __restrict__ Cout, float* __restrict__ lbuf) {
  __shared__ __align__(16) unsigned short As[2][4096];
  __shared__ __align__(16) unsigned short Bs[2][4096];

  constexpr int LDA = (MODE == 1) ? 3072 : 2048;

  const int wgid = blockIdx.x;
  int m0, n0, b;
  if constexpr (MODE == 1) {
    b = wgid & 3;
    const int t = wgid >> 2;                    // 0..135
    int bm = 0;
    while ((bm + 2) * (bm + 1) / 2 <= t) ++bm;
    const int bn = t - bm * (bm + 1) / 2;
    m0 = bm << 7; n0 = bn << 7;
  } else {
    const int xcd = wgid & 7;
    const int inner = wgid >> 3;                // 0..63
    const int s = inner >> 5;
    const int rem = inner & 31;
    b = rem >> 3;
    const int bn = rem & 7;
    const int bm = s ? (15 - xcd) : xcd;
    m0 = bm << 7; n0 = bn << 7;
  }

  const unsigned short* Ab = A;
  const unsigned short* Bb = Bp;
  if constexpr (MODE == 1) {
    Ab += (long)b * 2048 * 3072;
    Bb += (long)b * 2048 * 3072;
  } else {
    Ab += (long)b * 2048 * 2048;
    Bb += (long)b * 1024 * 2048;
  }

  const int tid = threadIdx.x;

  const int srow = tid >> 2;                       // 0..63
  const int sseg = (tid & 3) ^ ((srow >> 1) & 3);
  const unsigned short* sa = Ab + (long)(m0 + srow) * LDA + sseg * 8;
  const unsigned short* sb = Bb + (long)(n0 + srow) * LDA + sseg * 8;
  const long sRj = (long)64 * LDA;
  unsigned short* dA = &As[0][0] + tid * 8;
  unsigned short* dB = &Bs[0][0] + tid * 8;

#define STG(kt, s)                                                             \
  do {                                                                         \
    GLD_LDS16(sa + (kt) * 32, dA + (s) * 4096);                                \
    GLD_LDS16(sa + sRj + (kt) * 32, dA + (s) * 4096 + 2048);                   \
    GLD_LDS16(sb + (kt) * 32, dB + (s) * 4096);                                \
    GLD_LDS16(sb + sRj + (kt) * 32, dB + (s) * 4096 + 2048);                   \
  } while (0)

  const int lane = tid & 63;
  const int w = tid >> 6;
  const int wr = w >> 1;
  const int wc = w & 1;
  const int fr = lane & 15;
  const int kb = lane >> 4;
  const unsigned short* rA0 = &As[0][0] + wr * 64 * 32;
  const unsigned short* rB0 = &Bs[0][0] + wc * 64 * 32;

  const int rq = kb << 2;

  // r6: PV-only — hoist loop-invariant 1/l above the K-loop
  float il[4][4];
  if constexpr (MODE == 2) {
    const float* lrow = lbuf + b * 2048;
#pragma unroll
    for (int mf = 0; mf < 4; ++mf) {
      const int row = m0 + wr * 64 + mf * 16 + rq;
#pragma unroll
      for (int r = 0; r < 4; ++r) il[mf][r] = 1.0f / lrow[row + r];
    }
  }

  f32x4 acc[4][4];
#pragma unroll
  for (int mf = 0; mf < 4; ++mf)
#pragma unroll
    for (int nf = 0; nf < 4; ++nf)
      acc[mf][nf] = (f32x4){0.f, 0.f, 0.f, 0.f};

  const int kend = (MODE == 2) ? (m0 + 128) : 1024;
  const int NT = kend >> 5;

  STG(0, 0);
  __syncthreads();

  for (int kt = 0; kt < NT; ++kt) {
    const int s = kt & 1;
    if (kt + 1 < NT) STG(kt + 1, s ^ 1);

    bf16x8 av[4], bvv[4];
#pragma unroll
    for (int mf = 0; mf < 4; ++mf) {
      const int row = mf * 16 + fr;
      const int segr = (kb ^ ((row >> 1) & 3)) << 3;
      av[mf] = ldfrag(rA0 + s * 4096 + row * 32 + segr);
    }
#pragma unroll
    for (int nf = 0; nf < 4; ++nf) {
      const int row = nf * 16 + fr;
      const int segr = (kb ^ ((row >> 1) & 3)) << 3;
      bvv[nf] = ldfrag(rB0 + s * 4096 + row * 32 + segr);
    }

#pragma unroll
    for (int mf = 0; mf < 4; ++mf)
#pragma unroll
      for (int nf = 0; nf < 4; ++nf)
        acc[mf][nf] = __builtin_amdgcn_mfma_f32_16x16x32_bf16(av[mf], bvv[nf], acc[mf][nf], 0, 0, 0);

    __syncthreads();
  }
#undef STG

  if constexpr (MODE == 1) {
    unsigned short* Pu = (unsigned short*)Cout + (long)b * 2048 * 2048;
    float* lrow = lbuf + b * 2048;
#pragma unroll
    for (int mf = 0; mf < 4; ++mf) {
      const int row = m0 + wr * 64 + mf * 16 + rq;
      float psum0 = 0.f, psum1 = 0.f, psum2 = 0.f, psum3 = 0.f;
#pragma unroll
      for (int nf = 0; nf < 4; ++nf) {
        const int col = n0 + wc * 64 + nf * 16 + fr;
        float e0 = (col > row + 0) ? 0.f : __expf(acc[mf][nf][0] * 0.03125f);
        float e1 = (col > row + 1) ? 0.f : __expf(acc[mf][nf][1] * 0.03125f);
        float e2 = (col > row + 2) ? 0.f : __expf(acc[mf][nf][2] * 0.03125f);
        float e3 = (col > row + 3) ? 0.f : __expf(acc[mf][nf][3] * 0.03125f);
        psum0 += e0; psum1 += e1; psum2 += e2; psum3 += e3;
        Pu[(long)(row + 0) * 2048 + col] = f2bf(e0);
        Pu[(long)(row + 1) * 2048 + col] = f2bf(e1);
        Pu[(long)(row + 2) * 2048 + col] = f2bf(e2);
        Pu[(long)(row + 3) * 2048 + col] = f2bf(e3);
      }
      // reduce over the 16 fr-lanes (xor 1,2,4,8 stays in the 16-group)
#pragma unroll
      for (int off = 1; off < 16; off <<= 1) {
        psum0 += __shfl_xor(psum0, off);
        psum1 += __shfl_xor(psum1, off);
        psum2 += __shfl_xor(psum2, off);
        psum3 += __shfl_xor(psum3, off);
      }
      if (fr == 0) {
        atomicAdd(&lrow[row + 0], psum0);
        atomicAdd(&lrow[row + 1], psum1);
        atomicAdd(&lrow[row + 2], psum2);
        atomicAdd(&lrow[row + 3], psum3);
      }
    }
  } else {
    float* Cf = (float*)Cout + (long)b * 2048 * 1024;
#pragma unroll
    for (int mf = 0; mf < 4; ++mf) {
      const int row = m0 + wr * 64 + mf * 16 + rq;
#pragma unroll
      for (int nf = 0; nf < 4; ++nf) {
        const int col = n0 + wc * 64 + nf * 16 + fr;
        Cf[(long)(row + 0) * 1024 + col] = acc[mf][nf][0] * il[mf][0];
        Cf[(long)(row + 1) * 1024 + col] = acc[mf][nf][1] * il[mf][1];
        Cf[(long)(row + 2) * 1024 + col] = acc[mf][nf][2] * il[mf][2];
        Cf[(long)(row + 3) * 1024 + col] = acc[mf][nf][3] * il[mf][3];
      }
    }
  }
}

// ---------------------------------------------------------------------------
extern "C" void kernel_launch(void* const* d_in, const int* in_sizes, int n_in,
                              void* d_out, int out_size, void* d_ws, size_t ws_size,
                              hipStream_t stream) {
  const float* x  = (const float*)d_in[0];
  const float* Wq = (const float*)d_in[1];
  const float* Wk = (const float*)d_in[2];
  const float* Wv = (const float*)d_in[3];
  float* out = (float*)d_out;

  const int Bb = 4, T = 2048, C = 1024;
  const long BT = (long)Bb * T;  // 8192
  const int N3 = 3 * C;          // 3072

  char* ws = (char*)d_ws;
  unsigned short* xb   = (unsigned short*)ws; ws += BT * C * 2;            // 16 MB
  unsigned short* wbuf = (unsigned short*)ws; ws += (long)N3 * C * 2;      // 6 MB
  unsigned short* qkv  = (unsigned short*)ws; ws += BT * N3 * 2;           // 48 MB (v cols unused)
  unsigned short* vT   = (unsigned short*)ws; ws += BT * C * 2;            // 16 MB
  unsigned short* Pu   = (unsigned short*)ws; ws += (long)Bb * T * T * 2;  // 32 MB
  float* lbuf          = (float*)ws;          ws += BT * 4;                // 32 KB

  // 1. merged casts + zero l
  const long nx4 = BT * C / 4, nw4 = (long)C * C / 4;
  cast_all<<<2048, 256, 0, stream>>>(x, Wq, Wk, Wv, xb, lbuf, nx4, nw4, nx4 + 3 * nw4);

  // 2. fused QKV projection (128x256, 8 waves); v written transposed into vT
  gemm_qkv<<<dim3(768, 1, 1), 512, 0, stream>>>(xb, wbuf, qkv, vT);

  // 3. Pu = exp(q k^T / 32) (causal, no-max softmax) + atomic row sums -> l
  gemm128<1><<<dim3(544, 1, 1), 256, 0, stream>>>(qkv, qkv + C, Pu, lbuf);

  // 4. out = (Pu vT) / l (causal K, XCD-banded bn-sweep + per-XCD LPT)
  gemm128<2><<<dim3(512, 1, 1), 256, 0, stream>>>(Pu, vT, out, lbuf);
}